// Round 2
// baseline (1134.416 us; speedup 1.0000x reference)
//
#include <hip/hip_runtime.h>

// softmax(Q.V^T).V  — staged pipeline:
//   1) convert Q -> bf16 [Qhi|Qhi|Qlo], V -> bf16 [Vhi|Vlo|Vhi]  (K=3072)
//      so one bf16 GEMM gives Qhi.Vhi + Qhi.Vlo + Qlo.Vhi  (drops only Qlo.Vlo ~1e-4)
//   2) GEMM1: S = Qcat . Vcat^T   (bf16 MFMA, fp32 accum)
//   3) row softmax (fp32) -> P bf16
//   4) GEMM2: out = P . V   (B^T operand = precomputed V^T bf16)
// Batch-chunked by ws_size (~54.5 MB per batch needed).

#define B_ 16
#define LQ_ 2048
#define LV_ 2048
#define DD_ 1024
#define KCAT_ 3072

typedef unsigned short u16;
typedef __attribute__((ext_vector_type(8))) short bf16x8;
typedef __attribute__((ext_vector_type(4))) float f32x4;
typedef __attribute__((ext_vector_type(4))) unsigned short u16x4;

__device__ __forceinline__ u16 f2bf(float x) {
  unsigned u = __float_as_uint(x);
  unsigned r = u + 0x7FFFu + ((u >> 16) & 1u);
  return (u16)(r >> 16);
}
__device__ __forceinline__ float bf2f(u16 h) {
  return __uint_as_float(((unsigned)h) << 16);
}

__device__ __forceinline__ void gload16(const u16* g, u16* lds) {
  __builtin_amdgcn_global_load_lds(
      (const __attribute__((address_space(1))) void*)g,
      (__attribute__((address_space(3))) void*)lds, 16, 0, 0);
}

// fp32 [nrows][1024] -> u16 bf16 [nrows][3072]
// mode 0 (Q): [hi | hi | lo]   mode 1 (V): [hi | lo | hi]
__global__ __launch_bounds__(256) void k_conv3(const float* __restrict__ in,
                                               u16* __restrict__ out, int nrows, int mode) {
  int t = blockIdx.x * 256 + threadIdx.x;
  int total = nrows * (DD_ / 4);
  if (t >= total) return;
  int row = t >> 8;            // / (DD_/4)
  int c4 = (t & 255) << 2;     // *4
  float4 v = *(const float4*)(in + (size_t)row * DD_ + c4);
  u16x4 hi, lo;
  hi.x = f2bf(v.x); lo.x = f2bf(v.x - bf2f(hi.x));
  hi.y = f2bf(v.y); lo.y = f2bf(v.y - bf2f(hi.y));
  hi.z = f2bf(v.z); lo.z = f2bf(v.z - bf2f(hi.z));
  hi.w = f2bf(v.w); lo.w = f2bf(v.w - bf2f(hi.w));
  u16* o = out + (size_t)row * KCAT_ + c4;
  if (mode == 0) {
    *(u16x4*)(o) = hi;
    *(u16x4*)(o + DD_) = hi;
    *(u16x4*)(o + 2 * DD_) = lo;
  } else {
    *(u16x4*)(o) = hi;
    *(u16x4*)(o + DD_) = lo;
    *(u16x4*)(o + 2 * DD_) = hi;
  }
}

// V fp32 [LV][DD] -> VT bf16 [DD][LV]  (64x64 LDS tiles, padded)
__global__ __launch_bounds__(256) void k_vt(const float* __restrict__ V, u16* __restrict__ VT) {
  __shared__ u16 tile[64][65];
  const int d0 = blockIdx.x * 64, v0 = blockIdx.y * 64;
  const float* Vb = V + (size_t)blockIdx.z * LV_ * DD_;
  u16* VTb = VT + (size_t)blockIdx.z * DD_ * LV_;
  const int t = threadIdx.x;
  const int r = t >> 4, c4 = (t & 15) * 4;
#pragma unroll
  for (int i = 0; i < 4; ++i) {
    int row = r + i * 16;
    float4 x = *(const float4*)(Vb + (size_t)(v0 + row) * DD_ + d0 + c4);
    tile[row][c4 + 0] = f2bf(x.x);
    tile[row][c4 + 1] = f2bf(x.y);
    tile[row][c4 + 2] = f2bf(x.z);
    tile[row][c4 + 3] = f2bf(x.w);
  }
  __syncthreads();
#pragma unroll
  for (int i = 0; i < 4; ++i) {
    int row = r + i * 16;  // d-index within tile
    u16x4 o;
    o.x = tile[c4 + 0][row];
    o.y = tile[c4 + 1][row];
    o.z = tile[c4 + 2][row];
    o.w = tile[c4 + 3][row];
    *(u16x4*)(VTb + (size_t)(d0 + row) * LV_ + v0 + c4) = o;
  }
}

// C[M][N] = A[M][K] . Bt[N][K]^T   (bf16 in, fp32 out), batched via blockIdx.z
// 128x128 tile, BK=32, 4 waves each 64x64 (4x4 fragments of 16x16x32 MFMA)
__global__ __launch_bounds__(256) void k_gemm_bt(const u16* __restrict__ A,
                                                 const u16* __restrict__ Bt,
                                                 float* __restrict__ C,
                                                 int M, int N, int K) {
  __shared__ u16 ldsA[128 * 32];
  __shared__ u16 ldsB[128 * 32];
  const int tid = threadIdx.x;
  const int w = tid >> 6;
  const int l = tid & 63;
  const int m0 = blockIdx.y << 7;
  const int n0 = blockIdx.x << 7;
  const u16* Ab = A + (size_t)blockIdx.z * M * K;
  const u16* Bb = Bt + (size_t)blockIdx.z * N * K;
  float* Cb = C + (size_t)blockIdx.z * M * N;
  const int wr = w >> 1, wc = w & 1;
  f32x4 acc[4][4];
#pragma unroll
  for (int mi = 0; mi < 4; ++mi)
#pragma unroll
    for (int ni = 0; ni < 4; ++ni)
      acc[mi][ni] = (f32x4){0.f, 0.f, 0.f, 0.f};
  const int fr = l & 15;         // fragment row (m or n)
  const int fk = (l >> 4) * 8;   // fragment k start

  for (int kt = 0; kt < K; kt += 32) {
    // stage A,B 128x32 bf16 tiles: 512 x 16B slots each, 2 wave-loads per wave per tile
#pragma unroll
    for (int i = 0; i < 2; ++i) {
      const int sbase = w * 128 + i * 64;       // wave-uniform slot base
      const int slot = sbase + l;
      const int row = slot >> 2;
      const int col = (slot & 3) * 8;
      gload16(Ab + (size_t)(m0 + row) * K + kt + col, &ldsA[sbase * 8]);
      gload16(Bb + (size_t)(n0 + row) * K + kt + col, &ldsB[sbase * 8]);
    }
    __syncthreads();
    bf16x8 af[4], bfv[4];
#pragma unroll
    for (int mi = 0; mi < 4; ++mi)
      af[mi] = *(const bf16x8*)&ldsA[(wr * 64 + mi * 16 + fr) * 32 + fk];
#pragma unroll
    for (int ni = 0; ni < 4; ++ni)
      bfv[ni] = *(const bf16x8*)&ldsB[(wc * 64 + ni * 16 + fr) * 32 + fk];
#pragma unroll
    for (int mi = 0; mi < 4; ++mi)
#pragma unroll
      for (int ni = 0; ni < 4; ++ni)
        acc[mi][ni] = __builtin_amdgcn_mfma_f32_16x16x32_bf16(af[mi], bfv[ni], acc[mi][ni], 0, 0, 0);
    __syncthreads();
  }
  // epilogue: C/D layout col=lane&15, row=(lane>>4)*4+j  [m89-verified]
  const int crow = (l >> 4) * 4;
  const int ccol = l & 15;
#pragma unroll
  for (int mi = 0; mi < 4; ++mi)
#pragma unroll
    for (int ni = 0; ni < 4; ++ni) {
      float* cp = Cb + (size_t)(m0 + wr * 64 + mi * 16 + crow) * N + (n0 + wc * 64 + ni * 16 + ccol);
#pragma unroll
      for (int j = 0; j < 4; ++j)
        cp[(size_t)j * N] = acc[mi][ni][j];
    }
}

// row softmax over S [nrows][2048] fp32 -> P bf16 (one wave per row)
__global__ __launch_bounds__(256) void k_softmax(const float* __restrict__ S,
                                                 u16* __restrict__ P, int nrows) {
  const int w = threadIdx.x >> 6, l = threadIdx.x & 63;
  const int row = blockIdx.x * 4 + w;
  if (row >= nrows) return;
  const float* s = S + (size_t)row * LV_;
  u16* p = P + (size_t)row * LV_;
  float4 v[8];
  float m = -3.0e38f;
#pragma unroll
  for (int i = 0; i < 8; ++i) {
    v[i] = *(const float4*)(s + (l << 2) + (i << 8));
    m = fmaxf(m, fmaxf(fmaxf(v[i].x, v[i].y), fmaxf(v[i].z, v[i].w)));
  }
#pragma unroll
  for (int off = 32; off > 0; off >>= 1) m = fmaxf(m, __shfl_xor(m, off, 64));
  float4 e[8];
  float sum = 0.f;
#pragma unroll
  for (int i = 0; i < 8; ++i) {
    e[i].x = __expf(v[i].x - m);
    e[i].y = __expf(v[i].y - m);
    e[i].z = __expf(v[i].z - m);
    e[i].w = __expf(v[i].w - m);
    sum += e[i].x + e[i].y + e[i].z + e[i].w;
  }
#pragma unroll
  for (int off = 32; off > 0; off >>= 1) sum += __shfl_xor(sum, off, 64);
  const float inv = 1.0f / sum;
#pragma unroll
  for (int i = 0; i < 8; ++i) {
    u16x4 o;
    o.x = f2bf(e[i].x * inv);
    o.y = f2bf(e[i].y * inv);
    o.z = f2bf(e[i].z * inv);
    o.w = f2bf(e[i].w * inv);
    *(u16x4*)(p + (l << 2) + (i << 8)) = o;
  }
}

extern "C" void kernel_launch(void* const* d_in, const int* in_sizes, int n_in,
                              void* d_out, int out_size, void* d_ws, size_t ws_size,
                              hipStream_t stream) {
  const float* Q = (const float*)d_in[0];
  const float* V = (const float*)d_in[1];
  float* out = (float*)d_out;

  const size_t qcat_e = (size_t)LQ_ * KCAT_;  // u16 elems per batch
  const size_t vcat_e = (size_t)LV_ * KCAT_;
  const size_t vt_e = (size_t)DD_ * LV_;
  const size_t s_e = (size_t)LQ_ * LV_;       // f32
  const size_t p_e = (size_t)LQ_ * LV_;       // u16
  const size_t per_batch = qcat_e * 2 + vcat_e * 2 + vt_e * 2 + s_e * 4 + p_e * 2;

  int nb = (int)(ws_size / per_batch);
  if (nb < 1) nb = 1;
  if (nb > B_) nb = B_;

  char* wp = (char*)d_ws;
  u16* Qcat = (u16*)wp; wp += (size_t)nb * qcat_e * 2;
  u16* Vcat = (u16*)wp; wp += (size_t)nb * vcat_e * 2;
  u16* VT = (u16*)wp;   wp += (size_t)nb * vt_e * 2;
  float* S = (float*)wp; wp += (size_t)nb * s_e * 4;
  u16* P = (u16*)wp;

  for (int b0 = 0; b0 < B_; b0 += nb) {
    const int cb = (nb < B_ - b0) ? nb : (B_ - b0);
    const int rows = cb * LQ_;
    const int cthreads = rows * (DD_ / 4);
    k_conv3<<<dim3((cthreads + 255) / 256), dim3(256), 0, stream>>>(
        Q + (size_t)b0 * LQ_ * DD_, Qcat, rows, 0);
    k_conv3<<<dim3((cthreads + 255) / 256), dim3(256), 0, stream>>>(
        V + (size_t)b0 * LV_ * DD_, Vcat, rows, 1);
    k_vt<<<dim3(DD_ / 64, LV_ / 64, cb), dim3(256), 0, stream>>>(
        V + (size_t)b0 * LV_ * DD_, VT);
    k_gemm_bt<<<dim3(LV_ / 128, LQ_ / 128, cb), dim3(256), 0, stream>>>(
        Qcat, Vcat, S, LQ_, LV_, KCAT_);
    k_softmax<<<dim3(rows / 4), dim3(256), 0, stream>>>(S, P, rows);
    k_gemm_bt<<<dim3(DD_ / 128, LQ_ / 128, cb), dim3(256), 0, stream>>>(
        P, VT, out + (size_t)b0 * LQ_ * DD_, LQ_, DD_, LV_);
  }
}

// Round 3
// 1077.024 us; speedup vs baseline: 1.0533x; 1.0533x over previous
//
#include <hip/hip_runtime.h>

// softmax(Q.V^T).V — staged pipeline, de-materialized hi/lo:
//   1) k_conv_q : Q fp32 -> Qhi,Qlo bf16
//      k_conv_vt: V fp32 -> Vhi,Vlo bf16 + VT (=Vhi transposed) for GEMM2
//   2) GEMM1: S = Qhi.Vhi^T + Qhi.Vlo^T + Qlo.Vhi^T  (3 K=1024 segments, fp32 out)
//   3) row softmax (fp32) -> P bf16
//   4) GEMM2: out = P . VT^T
// Batch-chunked by ws_size (44 MB per batch needed).

#define B_ 16
#define LQ_ 2048
#define LV_ 2048
#define DD_ 1024

typedef unsigned short u16;
typedef __attribute__((ext_vector_type(8))) short bf16x8;
typedef __attribute__((ext_vector_type(4))) float f32x4;
typedef __attribute__((ext_vector_type(4))) unsigned short u16x4;

__device__ __forceinline__ u16 f2bf(float x) {
  unsigned u = __float_as_uint(x);
  unsigned r = u + 0x7FFFu + ((u >> 16) & 1u);
  return (u16)(r >> 16);
}
__device__ __forceinline__ float bf2f(u16 h) {
  return __uint_as_float(((unsigned)h) << 16);
}

__device__ __forceinline__ void gload16(const u16* g, u16* lds) {
  __builtin_amdgcn_global_load_lds(
      (const __attribute__((address_space(1))) void*)g,
      (__attribute__((address_space(3))) void*)lds, 16, 0, 0);
}

// XCD-aware bijective remap of flattened block id (requires nwg % 8 == 0)
__device__ __forceinline__ void xcd_remap(int& bx, int& by, int& bz) {
  const int gx = gridDim.x, gy = gridDim.y, gz = gridDim.z;
  const int lid = blockIdx.x + gx * (blockIdx.y + gy * blockIdx.z);
  const int nwg = gx * gy * gz;
  const int q = nwg >> 3;
  const int nid = (lid & 7) * q + (lid >> 3);
  bx = nid % gx;
  const int rem = nid / gx;
  by = rem % gy;
  bz = rem / gy;
}

// Q fp32 [nrows][1024] -> Qhi,Qlo bf16 [nrows][1024]
__global__ __launch_bounds__(256) void k_conv_q(const float* __restrict__ in,
                                                u16* __restrict__ hi_o,
                                                u16* __restrict__ lo_o, int nrows) {
  int t = blockIdx.x * 256 + threadIdx.x;
  int total = nrows * (DD_ / 4);
  if (t >= total) return;
  int row = t >> 8;
  int c4 = (t & 255) << 2;
  float4 v = *(const float4*)(in + (size_t)row * DD_ + c4);
  u16x4 hi, lo;
  hi.x = f2bf(v.x); lo.x = f2bf(v.x - bf2f(hi.x));
  hi.y = f2bf(v.y); lo.y = f2bf(v.y - bf2f(hi.y));
  hi.z = f2bf(v.z); lo.z = f2bf(v.z - bf2f(hi.z));
  hi.w = f2bf(v.w); lo.w = f2bf(v.w - bf2f(hi.w));
  *(u16x4*)(hi_o + (size_t)row * DD_ + c4) = hi;
  *(u16x4*)(lo_o + (size_t)row * DD_ + c4) = lo;
}

// V fp32 [LV][DD] -> Vhi,Vlo [LV][DD] + VT [DD][LV] (= hi transposed), 64x64 tiles
__global__ __launch_bounds__(256) void k_conv_vt(const float* __restrict__ V,
                                                 u16* __restrict__ Vhi,
                                                 u16* __restrict__ Vlo,
                                                 u16* __restrict__ VT) {
  __shared__ u16 tile[64][65];
  const int d0 = blockIdx.x * 64, v0 = blockIdx.y * 64;
  const size_t boff = (size_t)blockIdx.z * LV_ * DD_;
  const float* Vb = V + boff;
  u16* Vhb = Vhi + boff;
  u16* Vlb = Vlo + boff;
  u16* VTb = VT + (size_t)blockIdx.z * DD_ * LV_;
  const int t = threadIdx.x;
  const int r = t >> 4, c4 = (t & 15) * 4;
#pragma unroll
  for (int i = 0; i < 4; ++i) {
    int row = r + i * 16;
    float4 x = *(const float4*)(Vb + (size_t)(v0 + row) * DD_ + d0 + c4);
    u16x4 h, lo;
    h.x = f2bf(x.x); lo.x = f2bf(x.x - bf2f(h.x));
    h.y = f2bf(x.y); lo.y = f2bf(x.y - bf2f(h.y));
    h.z = f2bf(x.z); lo.z = f2bf(x.z - bf2f(h.z));
    h.w = f2bf(x.w); lo.w = f2bf(x.w - bf2f(h.w));
    *(u16x4*)(Vhb + (size_t)(v0 + row) * DD_ + d0 + c4) = h;
    *(u16x4*)(Vlb + (size_t)(v0 + row) * DD_ + d0 + c4) = lo;
    tile[row][c4 + 0] = h.x;
    tile[row][c4 + 1] = h.y;
    tile[row][c4 + 2] = h.z;
    tile[row][c4 + 3] = h.w;
  }
  __syncthreads();
#pragma unroll
  for (int i = 0; i < 4; ++i) {
    int row = r + i * 16;  // d-index within tile
    u16x4 o;
    o.x = tile[c4 + 0][row];
    o.y = tile[c4 + 1][row];
    o.z = tile[c4 + 2][row];
    o.w = tile[c4 + 3][row];
    *(u16x4*)(VTb + (size_t)(d0 + row) * LV_ + v0 + c4) = o;
  }
}

// GEMM1: S[2048][2048] fp32 = sum of 3 segments Ah.Bh + Ah.Bl + Al.Bh (all [2048][1024] bf16)
// 128x128 tile, BK=32, 4 waves x 4x4 fragments of 16x16x32 MFMA
__global__ __launch_bounds__(256) void k_gemm_s(const u16* __restrict__ Qhi,
                                                const u16* __restrict__ Qlo,
                                                const u16* __restrict__ Vhi,
                                                const u16* __restrict__ Vlo,
                                                float* __restrict__ S) {
  __shared__ u16 ldsA[128 * 32];
  __shared__ u16 ldsB[128 * 32];
  int bx, by, bz;
  xcd_remap(bx, by, bz);
  const int tid = threadIdx.x;
  const int w = tid >> 6;
  const int l = tid & 63;
  const int m0 = by << 7;
  const int n0 = bx << 7;
  const size_t boff = (size_t)bz * LQ_ * DD_;
  const u16* Ah = Qhi + boff;
  const u16* Al = Qlo + boff;
  const u16* Bh = Vhi + boff;
  const u16* Bl = Vlo + boff;
  float* Cb = S + (size_t)bz * LQ_ * LV_;
  const int wr = w >> 1, wc = w & 1;
  f32x4 acc[4][4];
#pragma unroll
  for (int mi = 0; mi < 4; ++mi)
#pragma unroll
    for (int ni = 0; ni < 4; ++ni)
      acc[mi][ni] = (f32x4){0.f, 0.f, 0.f, 0.f};
  const int fr = l & 15;
  const int fk = (l >> 4) * 8;

  auto seg = [&](const u16* As, const u16* Bs) {
    for (int kt = 0; kt < DD_; kt += 32) {
#pragma unroll
      for (int i = 0; i < 2; ++i) {
        const int sbase = w * 128 + i * 64;  // wave-uniform 16B-slot base
        const int slot = sbase + l;
        const int row = slot >> 2;
        const int col = (slot & 3) * 8;
        gload16(As + (size_t)(m0 + row) * DD_ + kt + col, &ldsA[sbase * 8]);
        gload16(Bs + (size_t)(n0 + row) * DD_ + kt + col, &ldsB[sbase * 8]);
      }
      __syncthreads();
      bf16x8 af[4], bfv[4];
#pragma unroll
      for (int mi = 0; mi < 4; ++mi)
        af[mi] = *(const bf16x8*)&ldsA[(wr * 64 + mi * 16 + fr) * 32 + fk];
#pragma unroll
      for (int ni = 0; ni < 4; ++ni)
        bfv[ni] = *(const bf16x8*)&ldsB[(wc * 64 + ni * 16 + fr) * 32 + fk];
#pragma unroll
      for (int mi = 0; mi < 4; ++mi)
#pragma unroll
        for (int ni = 0; ni < 4; ++ni)
          acc[mi][ni] = __builtin_amdgcn_mfma_f32_16x16x32_bf16(af[mi], bfv[ni], acc[mi][ni], 0, 0, 0);
      __syncthreads();
    }
  };
  seg(Ah, Bh);
  seg(Ah, Bl);
  seg(Al, Bh);

  const int crow = (l >> 4) * 4;
  const int ccol = l & 15;
#pragma unroll
  for (int mi = 0; mi < 4; ++mi)
#pragma unroll
    for (int ni = 0; ni < 4; ++ni) {
      float* cp = Cb + (size_t)(m0 + wr * 64 + mi * 16 + crow) * LV_ + (n0 + wc * 64 + ni * 16 + ccol);
#pragma unroll
      for (int j = 0; j < 4; ++j)
        cp[(size_t)j * LV_] = acc[mi][ni][j];
    }
}

// generic C[M][N] = A[M][K].Bt[N][K]^T (bf16), used for GEMM2 (P.VT^T)
__global__ __launch_bounds__(256) void k_gemm_bt(const u16* __restrict__ A,
                                                 const u16* __restrict__ Bt,
                                                 float* __restrict__ C,
                                                 int M, int N, int K) {
  __shared__ u16 ldsA[128 * 32];
  __shared__ u16 ldsB[128 * 32];
  int bx, by, bz;
  xcd_remap(bx, by, bz);
  const int tid = threadIdx.x;
  const int w = tid >> 6;
  const int l = tid & 63;
  const int m0 = by << 7;
  const int n0 = bx << 7;
  const u16* Ab = A + (size_t)bz * M * K;
  const u16* Bb = Bt + (size_t)bz * N * K;
  float* Cb = C + (size_t)bz * M * N;
  const int wr = w >> 1, wc = w & 1;
  f32x4 acc[4][4];
#pragma unroll
  for (int mi = 0; mi < 4; ++mi)
#pragma unroll
    for (int ni = 0; ni < 4; ++ni)
      acc[mi][ni] = (f32x4){0.f, 0.f, 0.f, 0.f};
  const int fr = l & 15;
  const int fk = (l >> 4) * 8;

  for (int kt = 0; kt < K; kt += 32) {
#pragma unroll
    for (int i = 0; i < 2; ++i) {
      const int sbase = w * 128 + i * 64;
      const int slot = sbase + l;
      const int row = slot >> 2;
      const int col = (slot & 3) * 8;
      gload16(Ab + (size_t)(m0 + row) * K + kt + col, &ldsA[sbase * 8]);
      gload16(Bb + (size_t)(n0 + row) * K + kt + col, &ldsB[sbase * 8]);
    }
    __syncthreads();
    bf16x8 af[4], bfv[4];
#pragma unroll
    for (int mi = 0; mi < 4; ++mi)
      af[mi] = *(const bf16x8*)&ldsA[(wr * 64 + mi * 16 + fr) * 32 + fk];
#pragma unroll
    for (int ni = 0; ni < 4; ++ni)
      bfv[ni] = *(const bf16x8*)&ldsB[(wc * 64 + ni * 16 + fr) * 32 + fk];
#pragma unroll
    for (int mi = 0; mi < 4; ++mi)
#pragma unroll
      for (int ni = 0; ni < 4; ++ni)
        acc[mi][ni] = __builtin_amdgcn_mfma_f32_16x16x32_bf16(af[mi], bfv[ni], acc[mi][ni], 0, 0, 0);
    __syncthreads();
  }
  const int crow = (l >> 4) * 4;
  const int ccol = l & 15;
#pragma unroll
  for (int mi = 0; mi < 4; ++mi)
#pragma unroll
    for (int ni = 0; ni < 4; ++ni) {
      float* cp = Cb + (size_t)(m0 + wr * 64 + mi * 16 + crow) * N + (n0 + wc * 64 + ni * 16 + ccol);
#pragma unroll
      for (int j = 0; j < 4; ++j)
        cp[(size_t)j * N] = acc[mi][ni][j];
    }
}

// row softmax over S [nrows][2048] fp32 -> P bf16 (one wave per row)
__global__ __launch_bounds__(256) void k_softmax(const float* __restrict__ S,
                                                 u16* __restrict__ P, int nrows) {
  const int w = threadIdx.x >> 6, l = threadIdx.x & 63;
  const int row = blockIdx.x * 4 + w;
  if (row >= nrows) return;
  const float* s = S + (size_t)row * LV_;
  u16* p = P + (size_t)row * LV_;
  float4 v[8];
  float m = -3.0e38f;
#pragma unroll
  for (int i = 0; i < 8; ++i) {
    v[i] = *(const float4*)(s + (l << 2) + (i << 8));
    m = fmaxf(m, fmaxf(fmaxf(v[i].x, v[i].y), fmaxf(v[i].z, v[i].w)));
  }
#pragma unroll
  for (int off = 32; off > 0; off >>= 1) m = fmaxf(m, __shfl_xor(m, off, 64));
  float sum = 0.f;
#pragma unroll
  for (int i = 0; i < 8; ++i) {
    v[i].x = __expf(v[i].x - m);
    v[i].y = __expf(v[i].y - m);
    v[i].z = __expf(v[i].z - m);
    v[i].w = __expf(v[i].w - m);
    sum += v[i].x + v[i].y + v[i].z + v[i].w;
  }
#pragma unroll
  for (int off = 32; off > 0; off >>= 1) sum += __shfl_xor(sum, off, 64);
  const float inv = 1.0f / sum;
#pragma unroll
  for (int i = 0; i < 8; ++i) {
    u16x4 o;
    o.x = f2bf(v[i].x * inv);
    o.y = f2bf(v[i].y * inv);
    o.z = f2bf(v[i].z * inv);
    o.w = f2bf(v[i].w * inv);
    *(u16x4*)(p + (l << 2) + (i << 8)) = o;
  }
}

extern "C" void kernel_launch(void* const* d_in, const int* in_sizes, int n_in,
                              void* d_out, int out_size, void* d_ws, size_t ws_size,
                              hipStream_t stream) {
  const float* Q = (const float*)d_in[0];
  const float* V = (const float*)d_in[1];
  float* out = (float*)d_out;

  const size_t qv_e = (size_t)LQ_ * DD_;   // elems per batch for Qhi/Qlo/Vhi/Vlo
  const size_t vt_e = (size_t)DD_ * LV_;
  const size_t s_e = (size_t)LQ_ * LV_;    // f32
  const size_t p_e = (size_t)LQ_ * LV_;    // u16
  const size_t per_batch = qv_e * 4 * 2 + vt_e * 2 + s_e * 4 + p_e * 2;

  int nb = (int)(ws_size / per_batch);
  if (nb < 1) nb = 1;
  if (nb > B_) nb = B_;

  char* wp = (char*)d_ws;
  u16* Qhi = (u16*)wp; wp += (size_t)nb * qv_e * 2;
  u16* Qlo = (u16*)wp; wp += (size_t)nb * qv_e * 2;
  u16* Vhi = (u16*)wp; wp += (size_t)nb * qv_e * 2;
  u16* Vlo = (u16*)wp; wp += (size_t)nb * qv_e * 2;
  u16* VT = (u16*)wp;  wp += (size_t)nb * vt_e * 2;
  float* S = (float*)wp; wp += (size_t)nb * s_e * 4;
  u16* P = (u16*)wp;

  for (int b0 = 0; b0 < B_; b0 += nb) {
    const int cb = (nb < B_ - b0) ? nb : (B_ - b0);
    const int rows = cb * LQ_;
    const int cthreads = rows * (DD_ / 4);
    k_conv_q<<<dim3((cthreads + 255) / 256), dim3(256), 0, stream>>>(
        Q + (size_t)b0 * LQ_ * DD_, Qhi, Qlo, rows);
    k_conv_vt<<<dim3(DD_ / 64, LV_ / 64, cb), dim3(256), 0, stream>>>(
        V + (size_t)b0 * LV_ * DD_, Vhi, Vlo, VT);
    k_gemm_s<<<dim3(LV_ / 128, LQ_ / 128, cb), dim3(256), 0, stream>>>(
        Qhi, Qlo, Vhi, Vlo, S);
    k_softmax<<<dim3(rows / 4), dim3(256), 0, stream>>>(S, P, rows);
    k_gemm_bt<<<dim3(DD_ / 128, LQ_ / 128, cb), dim3(256), 0, stream>>>(
        P, VT, out + (size_t)b0 * LQ_ * DD_, LQ_, DD_, LV_);
  }
}

// Round 4
// 792.400 us; speedup vs baseline: 1.4316x; 1.3592x over previous
//
#include <hip/hip_runtime.h>

// softmax(Q.V^T).V — staged pipeline:
//   conv:  Q -> Qhi,Qlo bf16;  V -> Vhi,Vlo bf16 + VT (=Vhi^T)
//   GEMM1: S = Qhi.Vhi^T + Qhi.Vlo^T + Qlo.Vhi^T   (3 K=1024 segments)
//   softmax(S) -> P bf16
//   GEMM2: out = P . VT^T
// GEMMs: 256x256 tile, BK=64, 8 waves, 8-phase schedule, counted vmcnt(6),
// XOR-swizzled LDS (granule ^= row&7) via pre-swizzled global source.

#define B_ 16
#define LQ_ 2048
#define LV_ 2048
#define DD_ 1024

typedef unsigned short u16;
typedef __attribute__((ext_vector_type(8))) short bf16x8;
typedef __attribute__((ext_vector_type(4))) float f32x4;
typedef __attribute__((ext_vector_type(4))) unsigned short u16x4;

__device__ __forceinline__ u16 f2bf(float x) {
  unsigned u = __float_as_uint(x);
  unsigned r = u + 0x7FFFu + ((u >> 16) & 1u);
  return (u16)(r >> 16);
}
__device__ __forceinline__ float bf2f(u16 h) {
  return __uint_as_float(((unsigned)h) << 16);
}

__device__ __forceinline__ void gload16(const u16* g, u16* lds) {
  __builtin_amdgcn_global_load_lds(
      (const __attribute__((address_space(1))) void*)g,
      (__attribute__((address_space(3))) void*)lds, 16, 0, 0);
}

#define BARRIER() do { asm volatile("" ::: "memory"); __builtin_amdgcn_s_barrier(); asm volatile("" ::: "memory"); } while (0)
#define WAITVM(N) asm volatile("s_waitcnt vmcnt(" #N ")" ::: "memory")

// ---------------- 256x256 8-phase GEMM ----------------
// C[M][N] = sum_seg A_seg[M][K].B_seg[N][K]^T, K = TPS*64 per segment.
template <int NSEG, int TPS>
__global__ __launch_bounds__(512, 2) void k_gemm8(
    const u16* __restrict__ A0, const u16* __restrict__ B0,
    const u16* __restrict__ A1, const u16* __restrict__ B1,
    const u16* __restrict__ A2, const u16* __restrict__ B2,
    float* __restrict__ C, int M, int N, int lda, int ldb,
    size_t aBatch, size_t bBatch) {
  constexpr int NT = NSEG * TPS;
  __shared__ u16 lds[65536];  // A: 2 bufs x 256x64 | B: 2 bufs x 256x64
  u16* ldsA = lds;
  u16* ldsB = lds + 32768;

  // XCD-aware bijective remap (nwg % 8 == 0)
  int bx, by, bz;
  {
    const int gx = gridDim.x, gy = gridDim.y;
    const int lid = blockIdx.x + gx * (blockIdx.y + gy * blockIdx.z);
    const int nwg = gx * gy * gridDim.z;
    const int q = nwg >> 3;
    const int nid = (lid & 7) * q + (lid >> 3);
    bx = nid % gx;
    const int rem = nid / gx;
    by = rem % gy;
    bz = rem / gy;
  }

  const int tid = threadIdx.x;
  const int w = tid >> 6, l = tid & 63;
  const int m0 = by << 8, n0 = bx << 8;
  const int wr = w >> 2, wc = w & 3;  // 2(M) x 4(N) waves -> 128x64 per wave
  const int wr128 = wr * 128, wc64 = wc * 64;
  const int fr = l & 15, kx = l >> 4, fr7 = l & 7;
  const int srow = l >> 3;
  const int gsrc8 = (((l & 7) ^ ((l >> 3) & 7)) << 3);  // inverse-swizzled src granule

  const u16* sA0 = A0 + (size_t)bz * aBatch;
  const u16* sB0 = B0 + (size_t)bz * bBatch;
  const u16* sA1 = A1 + (size_t)bz * aBatch;
  const u16* sB1 = B1 + (size_t)bz * bBatch;
  const u16* sA2 = A2 + (size_t)bz * aBatch;
  const u16* sB2 = B2 + (size_t)bz * bBatch;
  float* Cb = C + (size_t)bz * M * N;

#define PICKAB(tt, Ap_, Bp_)                          \
  const u16 *Ap_ = sA0, *Bp_ = sB0;                   \
  if (NSEG > 1) {                                     \
    const int sg_ = (tt) / TPS;                       \
    if (sg_ == 1) { Ap_ = sA1; Bp_ = sB1; }           \
    if (NSEG > 2 && sg_ == 2) { Ap_ = sA2; Bp_ = sB2; } \
  }

  // A half h covers tile rows {h*64..h*64+63} u {128+h*64..+63}
#define STAGE_A(tt, h)                                                          \
  do {                                                                          \
    PICKAB(tt, Ap_, Bp_); (void)Bp_;                                            \
    const int kk_ = ((tt) % TPS) * 64;                                          \
    u16* d0_ = ldsA + ((tt) & 1) * 16384 + ((h) * 64 + w * 8) * 64;             \
    const u16* g0_ = Ap_ + (size_t)(m0 + (h) * 64 + w * 8 + srow) * lda + kk_ + gsrc8; \
    gload16(g0_, d0_);                                                          \
    gload16(g0_ + (size_t)128 * lda, d0_ + 128 * 64);                           \
  } while (0)

  // B half h covers tile rows { k*64 + h*32 .. +31 : k=0..3 }
#define STAGE_B(tt, h)                                                          \
  do {                                                                          \
    PICKAB(tt, Ap_, Bp_); (void)Ap_;                                            \
    const int kk_ = ((tt) % TPS) * 64;                                          \
    const int rb_ = (w >> 2) * 64 + (h) * 32 + (w & 3) * 8;                     \
    u16* d0_ = ldsB + ((tt) & 1) * 16384 + rb_ * 64;                            \
    const u16* g0_ = Bp_ + (size_t)(n0 + rb_ + srow) * ldb + kk_ + gsrc8;       \
    gload16(g0_, d0_);                                                          \
    gload16(g0_ + (size_t)128 * ldb, d0_ + 128 * 64);                           \
  } while (0)

#define RA8(MOFF)                                                                   \
  {                                                                                 \
    _Pragma("unroll") for (int m_ = 0; m_ < 4; ++m_) {                              \
      _Pragma("unroll") for (int k_ = 0; k_ < 2; ++k_) {                            \
        af[m_][k_] = *(const bf16x8*)(ldsA + bufo +                                 \
            (wr128 + (MOFF) + m_ * 16 + fr) * 64 + (((kx + k_ * 4) ^ fr7) << 3));   \
      }                                                                             \
    }                                                                               \
  }

#define RB4(NF0)                                                                    \
  {                                                                                 \
    _Pragma("unroll") for (int n_ = 0; n_ < 2; ++n_) {                              \
      _Pragma("unroll") for (int k_ = 0; k_ < 2; ++k_) {                            \
        bf[(NF0) + n_][k_] = *(const bf16x8*)(ldsB + bufo +                         \
            (wc64 + ((NF0) + n_) * 16 + fr) * 64 + (((kx + k_ * 4) ^ fr7) << 3));   \
      }                                                                             \
    }                                                                               \
  }

#define MFMA8(MF0, NF0)                                                             \
  {                                                                                 \
    _Pragma("unroll") for (int m_ = 0; m_ < 4; ++m_)                                \
    _Pragma("unroll") for (int n_ = 0; n_ < 2; ++n_)                                \
    _Pragma("unroll") for (int k_ = 0; k_ < 2; ++k_)                                \
        acc[(MF0) + m_][(NF0) + n_] = __builtin_amdgcn_mfma_f32_16x16x32_bf16(      \
            af[m_][k_], bf[(NF0) + n_][k_], acc[(MF0) + m_][(NF0) + n_], 0, 0, 0);  \
  }

  f32x4 acc[8][4];
#pragma unroll
  for (int i = 0; i < 8; ++i)
#pragma unroll
    for (int j = 0; j < 4; ++j) acc[i][j] = (f32x4){0.f, 0.f, 0.f, 0.f};
  bf16x8 af[4][2], bf[4][2];

  // Prologue: tile0 fully + tile1 {Ah0,Bh0,Ah1}; wait until tile0 landed.
  STAGE_A(0, 0); STAGE_A(0, 1); STAGE_B(0, 0); STAGE_B(0, 1);
  STAGE_A(1, 0); STAGE_B(1, 0); STAGE_A(1, 1);
  WAITVM(6);
  BARRIER();

#pragma unroll 2
  for (int t = 0; t < NT; ++t) {
    const int bufo = (t & 1) * 16384;
    // ---- ph0: read A-half0 frags + B nf0..1; stage (t+1).Bh1
    RA8(0);
    RB4(0);
    if (t + 1 < NT) STAGE_B(t + 1, 1);
    BARRIER();
    __builtin_amdgcn_s_setprio(1); MFMA8(0, 0); __builtin_amdgcn_s_setprio(0);
    BARRIER();
    // ---- ph1: read B nf2..3; stage (t+2).Ah0
    RB4(2);
    if (t + 2 < NT) STAGE_A(t + 2, 0);
    BARRIER();
    __builtin_amdgcn_s_setprio(1); MFMA8(0, 2); __builtin_amdgcn_s_setprio(0);
    BARRIER();
    // ---- ph2: read A-half1 frags; stage (t+2).Bh0
    RA8(64);
    if (t + 2 < NT) STAGE_B(t + 2, 0);
    BARRIER();
    __builtin_amdgcn_s_setprio(1); MFMA8(4, 0); __builtin_amdgcn_s_setprio(0);
    BARRIER();
    // ---- ph3: stage (t+2).Ah1; counted vmcnt so next tile is resident
    if (t + 2 < NT) STAGE_A(t + 2, 1);
    BARRIER();
    __builtin_amdgcn_s_setprio(1); MFMA8(4, 2); __builtin_amdgcn_s_setprio(0);
    if (t + 2 < NT) { WAITVM(6); } else if (t + 1 < NT) { WAITVM(0); }
    BARRIER();
  }

  // Epilogue: C/D layout col=lane&15, row=(lane>>4)*4+j
  const int crow = (l >> 4) * 4;
  const int ccol = l & 15;
#pragma unroll
  for (int mf = 0; mf < 8; ++mf)
#pragma unroll
    for (int nf = 0; nf < 4; ++nf) {
      float* cp = Cb + (size_t)(m0 + wr128 + mf * 16 + crow) * N + (n0 + wc64 + nf * 16 + ccol);
#pragma unroll
      for (int j = 0; j < 4; ++j) cp[(size_t)j * N] = acc[mf][nf][j];
    }
#undef PICKAB
#undef STAGE_A
#undef STAGE_B
#undef RA8
#undef RB4
#undef MFMA8
}

// ---------------- aux kernels ----------------
__global__ __launch_bounds__(256) void k_conv_q(const float* __restrict__ in,
                                                u16* __restrict__ hi_o,
                                                u16* __restrict__ lo_o, int nrows) {
  int t = blockIdx.x * 256 + threadIdx.x;
  int total = nrows * (DD_ / 4);
  if (t >= total) return;
  int row = t >> 8;
  int c4 = (t & 255) << 2;
  float4 v = *(const float4*)(in + (size_t)row * DD_ + c4);
  u16x4 hi, lo;
  hi.x = f2bf(v.x); lo.x = f2bf(v.x - bf2f(hi.x));
  hi.y = f2bf(v.y); lo.y = f2bf(v.y - bf2f(hi.y));
  hi.z = f2bf(v.z); lo.z = f2bf(v.z - bf2f(hi.z));
  hi.w = f2bf(v.w); lo.w = f2bf(v.w - bf2f(hi.w));
  *(u16x4*)(hi_o + (size_t)row * DD_ + c4) = hi;
  *(u16x4*)(lo_o + (size_t)row * DD_ + c4) = lo;
}

__global__ __launch_bounds__(256) void k_conv_vt(const float* __restrict__ V,
                                                 u16* __restrict__ Vhi,
                                                 u16* __restrict__ Vlo,
                                                 u16* __restrict__ VT) {
  __shared__ u16 tile[64][65];
  const int d0 = blockIdx.x * 64, v0 = blockIdx.y * 64;
  const size_t boff = (size_t)blockIdx.z * LV_ * DD_;
  const float* Vb = V + boff;
  u16* Vhb = Vhi + boff;
  u16* Vlb = Vlo + boff;
  u16* VTb = VT + (size_t)blockIdx.z * DD_ * LV_;
  const int t = threadIdx.x;
  const int r = t >> 4, c4 = (t & 15) * 4;
#pragma unroll
  for (int i = 0; i < 4; ++i) {
    int row = r + i * 16;
    float4 x = *(const float4*)(Vb + (size_t)(v0 + row) * DD_ + d0 + c4);
    u16x4 h, lo;
    h.x = f2bf(x.x); lo.x = f2bf(x.x - bf2f(h.x));
    h.y = f2bf(x.y); lo.y = f2bf(x.y - bf2f(h.y));
    h.z = f2bf(x.z); lo.z = f2bf(x.z - bf2f(h.z));
    h.w = f2bf(x.w); lo.w = f2bf(x.w - bf2f(h.w));
    *(u16x4*)(Vhb + (size_t)(v0 + row) * DD_ + d0 + c4) = h;
    *(u16x4*)(Vlb + (size_t)(v0 + row) * DD_ + d0 + c4) = lo;
    tile[row][c4 + 0] = h.x;
    tile[row][c4 + 1] = h.y;
    tile[row][c4 + 2] = h.z;
    tile[row][c4 + 3] = h.w;
  }
  __syncthreads();
#pragma unroll
  for (int i = 0; i < 4; ++i) {
    int row = r + i * 16;
    u16x4 o;
    o.x = tile[c4 + 0][row];
    o.y = tile[c4 + 1][row];
    o.z = tile[c4 + 2][row];
    o.w = tile[c4 + 3][row];
    *(u16x4*)(VTb + (size_t)(d0 + row) * LV_ + v0 + c4) = o;
  }
}

__global__ __launch_bounds__(256) void k_softmax(const float* __restrict__ S,
                                                 u16* __restrict__ P, int nrows) {
  const int w = threadIdx.x >> 6, l = threadIdx.x & 63;
  const int row = blockIdx.x * 4 + w;
  if (row >= nrows) return;
  const float* s = S + (size_t)row * LV_;
  u16* p = P + (size_t)row * LV_;
  float4 v[8];
  float m = -3.0e38f;
#pragma unroll
  for (int i = 0; i < 8; ++i) {
    v[i] = *(const float4*)(s + (l << 2) + (i << 8));
    m = fmaxf(m, fmaxf(fmaxf(v[i].x, v[i].y), fmaxf(v[i].z, v[i].w)));
  }
#pragma unroll
  for (int off = 32; off > 0; off >>= 1) m = fmaxf(m, __shfl_xor(m, off, 64));
  float sum = 0.f;
#pragma unroll
  for (int i = 0; i < 8; ++i) {
    v[i].x = __expf(v[i].x - m);
    v[i].y = __expf(v[i].y - m);
    v[i].z = __expf(v[i].z - m);
    v[i].w = __expf(v[i].w - m);
    sum += v[i].x + v[i].y + v[i].z + v[i].w;
  }
#pragma unroll
  for (int off = 32; off > 0; off >>= 1) sum += __shfl_xor(sum, off, 64);
  const float inv = 1.0f / sum;
#pragma unroll
  for (int i = 0; i < 8; ++i) {
    u16x4 o;
    o.x = f2bf(v[i].x * inv);
    o.y = f2bf(v[i].y * inv);
    o.z = f2bf(v[i].z * inv);
    o.w = f2bf(v[i].w * inv);
    *(u16x4*)(p + (l << 2) + (i << 8)) = o;
  }
}

extern "C" void kernel_launch(void* const* d_in, const int* in_sizes, int n_in,
                              void* d_out, int out_size, void* d_ws, size_t ws_size,
                              hipStream_t stream) {
  const float* Q = (const float*)d_in[0];
  const float* V = (const float*)d_in[1];
  float* out = (float*)d_out;

  const size_t qv_e = (size_t)LQ_ * DD_;
  const size_t vt_e = (size_t)DD_ * LV_;
  const size_t s_e = (size_t)LQ_ * LV_;
  const size_t p_e = (size_t)LQ_ * LV_;
  const size_t per_batch = qv_e * 4 * 2 + vt_e * 2 + s_e * 4 + p_e * 2;

  int nb = (int)(ws_size / per_batch);
  if (nb < 1) nb = 1;
  if (nb > B_) nb = B_;

  char* wp = (char*)d_ws;
  u16* Qhi = (u16*)wp; wp += (size_t)nb * qv_e * 2;
  u16* Qlo = (u16*)wp; wp += (size_t)nb * qv_e * 2;
  u16* Vhi = (u16*)wp; wp += (size_t)nb * qv_e * 2;
  u16* Vlo = (u16*)wp; wp += (size_t)nb * qv_e * 2;
  u16* VT = (u16*)wp;  wp += (size_t)nb * vt_e * 2;
  float* S = (float*)wp; wp += (size_t)nb * s_e * 4;
  u16* P = (u16*)wp;

  for (int b0 = 0; b0 < B_; b0 += nb) {
    const int cb = (nb < B_ - b0) ? nb : (B_ - b0);
    const int rows = cb * LQ_;
    const int cthreads = rows * (DD_ / 4);
    k_conv_q<<<dim3((cthreads + 255) / 256), dim3(256), 0, stream>>>(
        Q + (size_t)b0 * LQ_ * DD_, Qhi, Qlo, rows);
    k_conv_vt<<<dim3(DD_ / 64, LV_ / 64, cb), dim3(256), 0, stream>>>(
        V + (size_t)b0 * LV_ * DD_, Vhi, Vlo, VT);
    k_gemm8<3, 16><<<dim3(LV_ / 256, LQ_ / 256, cb), dim3(512), 0, stream>>>(
        Qhi, Vhi, Qhi, Vlo, Qlo, Vhi, S, LQ_, LV_, DD_, DD_, qv_e, qv_e);
    k_softmax<<<dim3(rows / 4), dim3(256), 0, stream>>>(S, P, rows);
    k_gemm8<1, 32><<<dim3(DD_ / 256, LQ_ / 256, cb), dim3(512), 0, stream>>>(
        P, VT, P, VT, P, VT, out + (size_t)b0 * LQ_ * DD_, LQ_, DD_, LV_, LV_, p_e, vt_e);
  }
}

// Round 5
// 615.326 us; speedup vs baseline: 1.8436x; 1.2878x over previous
//
#include <hip/hip_runtime.h>

// softmax(Q.V^T).V — staged pipeline, fp16 2-segment decomposition:
//   conv:  Q -> Qh fp16;  V -> Vh,Vl fp16 + VT (=Vh^T)
//   GEMM1: S = Qh.Vh^T + Qh.Vl^T   (2 K=1024 segments; drops Ql.Vh ~4.5e-3 sigma)
//   softmax(S) -> P fp16
//   GEMM2: out = P . VT^T
// GEMMs: 256x256 tile, BK=64, 8 waves, 8-phase schedule, counted vmcnt(6),
// XOR-swizzled LDS (granule ^= row&7) via pre-swizzled global source.

#define B_ 16
#define LQ_ 2048
#define LV_ 2048
#define DD_ 1024

typedef unsigned short u16;
typedef _Float16 f16x8 __attribute__((ext_vector_type(8)));
typedef __attribute__((ext_vector_type(4))) float f32x4;
typedef __attribute__((ext_vector_type(4))) unsigned short u16x4;

__device__ __forceinline__ u16 f2h(float x) {
  union { _Float16 h; u16 u; } c;
  c.h = (_Float16)x;
  return c.u;
}
__device__ __forceinline__ float h2f(u16 u) {
  union { _Float16 h; u16 u; } c;
  c.u = u;
  return (float)c.h;
}

__device__ __forceinline__ void gload16(const u16* g, u16* lds) {
  __builtin_amdgcn_global_load_lds(
      (const __attribute__((address_space(1))) void*)g,
      (__attribute__((address_space(3))) void*)lds, 16, 0, 0);
}

#define BARRIER() do { asm volatile("" ::: "memory"); __builtin_amdgcn_s_barrier(); asm volatile("" ::: "memory"); } while (0)
#define WAITVM(N) asm volatile("s_waitcnt vmcnt(" #N ")" ::: "memory")

// ---------------- 256x256 8-phase GEMM (fp16) ----------------
// C[M][N] = sum_seg A_seg[M][K].B_seg[N][K]^T, K = TPS*64 per segment.
template <int NSEG, int TPS>
__global__ __launch_bounds__(512, 2) void k_gemm8(
    const u16* __restrict__ A0, const u16* __restrict__ B0,
    const u16* __restrict__ A1, const u16* __restrict__ B1,
    float* __restrict__ C, int M, int N, int lda, int ldb,
    size_t aBatch, size_t bBatch) {
  constexpr int NT = NSEG * TPS;
  __shared__ u16 lds[65536];  // A: 2 bufs x 256x64 | B: 2 bufs x 256x64
  u16* ldsA = lds;
  u16* ldsB = lds + 32768;

  // XCD-aware bijective remap (nwg % 8 == 0)
  int bx, by, bz;
  {
    const int gx = gridDim.x, gy = gridDim.y;
    const int lid = blockIdx.x + gx * (blockIdx.y + gy * blockIdx.z);
    const int nwg = gx * gy * gridDim.z;
    const int q = nwg >> 3;
    const int nid = (lid & 7) * q + (lid >> 3);
    bx = nid % gx;
    const int rem = nid / gx;
    by = rem % gy;
    bz = rem / gy;
  }

  const int tid = threadIdx.x;
  const int w = tid >> 6, l = tid & 63;
  const int m0 = by << 8, n0 = bx << 8;
  const int wr = w >> 2, wc = w & 3;  // 2(M) x 4(N) waves -> 128x64 per wave
  const int wr128 = wr * 128, wc64 = wc * 64;
  const int fr = l & 15, kx = l >> 4, fr7 = l & 7;
  const int srow = l >> 3;
  const int gsrc8 = (((l & 7) ^ ((l >> 3) & 7)) << 3);  // inverse-swizzled src granule

  const u16* sA0 = A0 + (size_t)bz * aBatch;
  const u16* sB0 = B0 + (size_t)bz * bBatch;
  const u16* sA1 = A1 + (size_t)bz * aBatch;
  const u16* sB1 = B1 + (size_t)bz * bBatch;
  float* Cb = C + (size_t)bz * M * N;

#define PICKAB(tt, Ap_, Bp_)                          \
  const u16 *Ap_ = sA0, *Bp_ = sB0;                   \
  if (NSEG > 1 && (tt) / TPS == 1) { Ap_ = sA1; Bp_ = sB1; }

  // A half h covers tile rows {h*64..h*64+63} u {128+h*64..+63}
#define STAGE_A(tt, h)                                                          \
  do {                                                                          \
    PICKAB(tt, Ap_, Bp_); (void)Bp_;                                            \
    const int kk_ = ((tt) % TPS) * 64;                                          \
    u16* d0_ = ldsA + ((tt) & 1) * 16384 + ((h) * 64 + w * 8) * 64;             \
    const u16* g0_ = Ap_ + (size_t)(m0 + (h) * 64 + w * 8 + srow) * lda + kk_ + gsrc8; \
    gload16(g0_, d0_);                                                          \
    gload16(g0_ + (size_t)128 * lda, d0_ + 128 * 64);                           \
  } while (0)

  // B half h covers tile rows { k*64 + h*32 .. +31 : k=0..3 }
#define STAGE_B(tt, h)                                                          \
  do {                                                                          \
    PICKAB(tt, Ap_, Bp_); (void)Ap_;                                            \
    const int kk_ = ((tt) % TPS) * 64;                                          \
    const int rb_ = (w >> 2) * 64 + (h) * 32 + (w & 3) * 8;                     \
    u16* d0_ = ldsB + ((tt) & 1) * 16384 + rb_ * 64;                            \
    const u16* g0_ = Bp_ + (size_t)(n0 + rb_ + srow) * ldb + kk_ + gsrc8;       \
    gload16(g0_, d0_);                                                          \
    gload16(g0_ + (size_t)128 * ldb, d0_ + 128 * 64);                           \
  } while (0)

#define RA8(MOFF)                                                                   \
  {                                                                                 \
    _Pragma("unroll") for (int m_ = 0; m_ < 4; ++m_) {                              \
      _Pragma("unroll") for (int k_ = 0; k_ < 2; ++k_) {                            \
        af[m_][k_] = *(const f16x8*)(ldsA + bufo +                                  \
            (wr128 + (MOFF) + m_ * 16 + fr) * 64 + (((kx + k_ * 4) ^ fr7) << 3));   \
      }                                                                             \
    }                                                                               \
  }

#define RB4(NF0)                                                                    \
  {                                                                                 \
    _Pragma("unroll") for (int n_ = 0; n_ < 2; ++n_) {                              \
      _Pragma("unroll") for (int k_ = 0; k_ < 2; ++k_) {                            \
        bf[(NF0) + n_][k_] = *(const f16x8*)(ldsB + bufo +                          \
            (wc64 + ((NF0) + n_) * 16 + fr) * 64 + (((kx + k_ * 4) ^ fr7) << 3));   \
      }                                                                             \
    }                                                                               \
  }

#define MFMA8(MF0, NF0)                                                             \
  {                                                                                 \
    _Pragma("unroll") for (int m_ = 0; m_ < 4; ++m_)                                \
    _Pragma("unroll") for (int n_ = 0; n_ < 2; ++n_)                                \
    _Pragma("unroll") for (int k_ = 0; k_ < 2; ++k_)                                \
        acc[(MF0) + m_][(NF0) + n_] = __builtin_amdgcn_mfma_f32_16x16x32_f16(       \
            af[m_][k_], bf[(NF0) + n_][k_], acc[(MF0) + m_][(NF0) + n_], 0, 0, 0);  \
  }

  f32x4 acc[8][4];
#pragma unroll
  for (int i = 0; i < 8; ++i)
#pragma unroll
    for (int j = 0; j < 4; ++j) acc[i][j] = (f32x4){0.f, 0.f, 0.f, 0.f};
  f16x8 af[4][2], bf[4][2];

  // Prologue: tile0 fully + tile1 {Ah0,Bh0,Ah1}; wait until tile0 landed.
  STAGE_A(0, 0); STAGE_A(0, 1); STAGE_B(0, 0); STAGE_B(0, 1);
  STAGE_A(1, 0); STAGE_B(1, 0); STAGE_A(1, 1);
  WAITVM(6);
  BARRIER();

#pragma unroll 2
  for (int t = 0; t < NT; ++t) {
    const int bufo = (t & 1) * 16384;
    // ---- ph0: read A-half0 frags + B nf0..1; stage (t+1).Bh1
    RA8(0);
    RB4(0);
    if (t + 1 < NT) STAGE_B(t + 1, 1);
    BARRIER();
    __builtin_amdgcn_s_setprio(1); MFMA8(0, 0); __builtin_amdgcn_s_setprio(0);
    BARRIER();
    // ---- ph1: read B nf2..3; stage (t+2).Ah0
    RB4(2);
    if (t + 2 < NT) STAGE_A(t + 2, 0);
    BARRIER();
    __builtin_amdgcn_s_setprio(1); MFMA8(0, 2); __builtin_amdgcn_s_setprio(0);
    BARRIER();
    // ---- ph2: read A-half1 frags; stage (t+2).Bh0
    RA8(64);
    if (t + 2 < NT) STAGE_B(t + 2, 0);
    BARRIER();
    __builtin_amdgcn_s_setprio(1); MFMA8(4, 0); __builtin_amdgcn_s_setprio(0);
    BARRIER();
    // ---- ph3: stage (t+2).Ah1; counted vmcnt so next tile is resident
    if (t + 2 < NT) STAGE_A(t + 2, 1);
    BARRIER();
    __builtin_amdgcn_s_setprio(1); MFMA8(4, 2); __builtin_amdgcn_s_setprio(0);
    if (t + 2 < NT) { WAITVM(6); } else if (t + 1 < NT) { WAITVM(0); }
    BARRIER();
  }

  // Epilogue: C/D layout col=lane&15, row=(lane>>4)*4+j
  const int crow = (l >> 4) * 4;
  const int ccol = l & 15;
#pragma unroll
  for (int mf = 0; mf < 8; ++mf)
#pragma unroll
    for (int nf = 0; nf < 4; ++nf) {
      float* cp = Cb + (size_t)(m0 + wr128 + mf * 16 + crow) * N + (n0 + wc64 + nf * 16 + ccol);
#pragma unroll
      for (int j = 0; j < 4; ++j) cp[(size_t)j * N] = acc[mf][nf][j];
    }
#undef PICKAB
#undef STAGE_A
#undef STAGE_B
#undef RA8
#undef RB4
#undef MFMA8
}

// ---------------- aux kernels ----------------
// Q fp32 [nrows][1024] -> Qh fp16
__global__ __launch_bounds__(256) void k_conv_q(const float* __restrict__ in,
                                                u16* __restrict__ hi_o, int nrows) {
  int t = blockIdx.x * 256 + threadIdx.x;
  int total = nrows * (DD_ / 4);
  if (t >= total) return;
  int row = t >> 8;
  int c4 = (t & 255) << 2;
  float4 v = *(const float4*)(in + (size_t)row * DD_ + c4);
  u16x4 hi;
  hi.x = f2h(v.x);
  hi.y = f2h(v.y);
  hi.z = f2h(v.z);
  hi.w = f2h(v.w);
  *(u16x4*)(hi_o + (size_t)row * DD_ + c4) = hi;
}

// V fp32 [LV][DD] -> Vh,Vl fp16 [LV][DD] + VT fp16 [DD][LV] (= Vh^T), 64x64 tiles
__global__ __launch_bounds__(256) void k_conv_vt(const float* __restrict__ V,
                                                 u16* __restrict__ Vh,
                                                 u16* __restrict__ Vl,
                                                 u16* __restrict__ VT) {
  __shared__ u16 tile[64][65];
  const int d0 = blockIdx.x * 64, v0 = blockIdx.y * 64;
  const size_t boff = (size_t)blockIdx.z * LV_ * DD_;
  const float* Vb = V + boff;
  u16* Vhb = Vh + boff;
  u16* Vlb = Vl + boff;
  u16* VTb = VT + (size_t)blockIdx.z * DD_ * LV_;
  const int t = threadIdx.x;
  const int r = t >> 4, c4 = (t & 15) * 4;
#pragma unroll
  for (int i = 0; i < 4; ++i) {
    int row = r + i * 16;
    float4 x = *(const float4*)(Vb + (size_t)(v0 + row) * DD_ + d0 + c4);
    u16x4 h, lo;
    h.x = f2h(x.x); lo.x = f2h(x.x - h2f(h.x));
    h.y = f2h(x.y); lo.y = f2h(x.y - h2f(h.y));
    h.z = f2h(x.z); lo.z = f2h(x.z - h2f(h.z));
    h.w = f2h(x.w); lo.w = f2h(x.w - h2f(h.w));
    *(u16x4*)(Vhb + (size_t)(v0 + row) * DD_ + d0 + c4) = h;
    *(u16x4*)(Vlb + (size_t)(v0 + row) * DD_ + d0 + c4) = lo;
    tile[row][c4 + 0] = h.x;
    tile[row][c4 + 1] = h.y;
    tile[row][c4 + 2] = h.z;
    tile[row][c4 + 3] = h.w;
  }
  __syncthreads();
#pragma unroll
  for (int i = 0; i < 4; ++i) {
    int row = r + i * 16;
    u16x4 o;
    o.x = tile[c4 + 0][row];
    o.y = tile[c4 + 1][row];
    o.z = tile[c4 + 2][row];
    o.w = tile[c4 + 3][row];
    *(u16x4*)(VTb + (size_t)(d0 + row) * LV_ + v0 + c4) = o;
  }
}

// row softmax over S [nrows][2048] fp32 -> P fp16 (one wave per row)
__global__ __launch_bounds__(256) void k_softmax(const float* __restrict__ S,
                                                 u16* __restrict__ P, int nrows) {
  const int w = threadIdx.x >> 6, l = threadIdx.x & 63;
  const int row = blockIdx.x * 4 + w;
  if (row >= nrows) return;
  const float* s = S + (size_t)row * LV_;
  u16* p = P + (size_t)row * LV_;
  float4 v[8];
  float m = -3.0e38f;
#pragma unroll
  for (int i = 0; i < 8; ++i) {
    v[i] = *(const float4*)(s + (l << 2) + (i << 8));
    m = fmaxf(m, fmaxf(fmaxf(v[i].x, v[i].y), fmaxf(v[i].z, v[i].w)));
  }
#pragma unroll
  for (int off = 32; off > 0; off >>= 1) m = fmaxf(m, __shfl_xor(m, off, 64));
  float sum = 0.f;
#pragma unroll
  for (int i = 0; i < 8; ++i) {
    v[i].x = __expf(v[i].x - m);
    v[i].y = __expf(v[i].y - m);
    v[i].z = __expf(v[i].z - m);
    v[i].w = __expf(v[i].w - m);
    sum += v[i].x + v[i].y + v[i].z + v[i].w;
  }
#pragma unroll
  for (int off = 32; off > 0; off >>= 1) sum += __shfl_xor(sum, off, 64);
  const float inv = 1.0f / sum;
#pragma unroll
  for (int i = 0; i < 8; ++i) {
    u16x4 o;
    o.x = f2h(v[i].x * inv);
    o.y = f2h(v[i].y * inv);
    o.z = f2h(v[i].z * inv);
    o.w = f2h(v[i].w * inv);
    *(u16x4*)(p + (l << 2) + (i << 8)) = o;
  }
}

extern "C" void kernel_launch(void* const* d_in, const int* in_sizes, int n_in,
                              void* d_out, int out_size, void* d_ws, size_t ws_size,
                              hipStream_t stream) {
  const float* Q = (const float*)d_in[0];
  const float* V = (const float*)d_in[1];
  float* out = (float*)d_out;

  const size_t qv_e = (size_t)LQ_ * DD_;
  const size_t vt_e = (size_t)DD_ * LV_;
  const size_t s_e = (size_t)LQ_ * LV_;
  const size_t p_e = (size_t)LQ_ * LV_;
  const size_t per_batch = qv_e * 3 * 2 + vt_e * 2 + s_e * 4 + p_e * 2;  // 40 MiB

  int nb = (int)(ws_size / per_batch);
  if (nb < 1) nb = 1;
  if (nb > B_) nb = B_;

  char* wp = (char*)d_ws;
  u16* Qh = (u16*)wp; wp += (size_t)nb * qv_e * 2;
  u16* Vh = (u16*)wp; wp += (size_t)nb * qv_e * 2;
  u16* Vl = (u16*)wp; wp += (size_t)nb * qv_e * 2;
  u16* VT = (u16*)wp; wp += (size_t)nb * vt_e * 2;
  float* S = (float*)wp; wp += (size_t)nb * s_e * 4;
  u16* P = (u16*)wp;

  for (int b0 = 0; b0 < B_; b0 += nb) {
    const int cb = (nb < B_ - b0) ? nb : (B_ - b0);
    const int rows = cb * LQ_;
    const int cthreads = rows * (DD_ / 4);
    k_conv_q<<<dim3((cthreads + 255) / 256), dim3(256), 0, stream>>>(
        Q + (size_t)b0 * LQ_ * DD_, Qh, rows);
    k_conv_vt<<<dim3(DD_ / 64, LV_ / 64, cb), dim3(256), 0, stream>>>(
        V + (size_t)b0 * LV_ * DD_, Vh, Vl, VT);
    k_gemm8<2, 16><<<dim3(LV_ / 256, LQ_ / 256, cb), dim3(512), 0, stream>>>(
        Qh, Vh, Qh, Vl, S, LQ_, LV_, DD_, DD_, qv_e, qv_e);
    k_softmax<<<dim3(rows / 4), dim3(256), 0, stream>>>(S, P, rows);
    k_gemm8<1, 32><<<dim3(DD_ / 256, LQ_ / 256, cb), dim3(512), 0, stream>>>(
        P, VT, P, VT, out + (size_t)b0 * LQ_ * DD_, LQ_, DD_, LV_, LV_, p_e, vt_e);
  }
}

// Round 6
// 514.160 us; speedup vs baseline: 2.2063x; 1.1968x over previous
//
#include <hip/hip_runtime.h>

// softmax(Q.V^T).V — staged pipeline, plain fp16 single-segment:
//   conv:  Q -> Qh fp16;  V -> Vh fp16 + VT (=Vh^T)
//   GEMM1: S = Qh.Vh^T      (K=1024; drops both cross terms, S err sigma ~6.4e-3)
//   softmax(S) -> P fp16
//   GEMM2: out = P . VT^T
// GEMMs: 256x256 tile, BK=64, 8 waves, 8-phase schedule, counted vmcnt(6),
// XOR-swizzled LDS (granule ^= row&7) via pre-swizzled global source.

#define B_ 16
#define LQ_ 2048
#define LV_ 2048
#define DD_ 1024

typedef unsigned short u16;
typedef _Float16 f16x8 __attribute__((ext_vector_type(8)));
typedef __attribute__((ext_vector_type(4))) float f32x4;
typedef __attribute__((ext_vector_type(4))) unsigned short u16x4;

__device__ __forceinline__ u16 f2h(float x) {
  union { _Float16 h; u16 u; } c;
  c.h = (_Float16)x;
  return c.u;
}

__device__ __forceinline__ void gload16(const u16* g, u16* lds) {
  __builtin_amdgcn_global_load_lds(
      (const __attribute__((address_space(1))) void*)g,
      (__attribute__((address_space(3))) void*)lds, 16, 0, 0);
}

#define BARRIER() do { asm volatile("" ::: "memory"); __builtin_amdgcn_s_barrier(); asm volatile("" ::: "memory"); } while (0)
#define WAITVM(N) asm volatile("s_waitcnt vmcnt(" #N ")" ::: "memory")

// ---------------- 256x256 8-phase GEMM (fp16) ----------------
// C[M][N] = sum_seg A_seg[M][K].B_seg[N][K]^T, K = TPS*64 per segment.
template <int NSEG, int TPS>
__global__ __launch_bounds__(512, 2) void k_gemm8(
    const u16* __restrict__ A0, const u16* __restrict__ B0,
    const u16* __restrict__ A1, const u16* __restrict__ B1,
    float* __restrict__ C, int M, int N, int lda, int ldb,
    size_t aBatch, size_t bBatch) {
  constexpr int NT = NSEG * TPS;
  __shared__ u16 lds[65536];  // A: 2 bufs x 256x64 | B: 2 bufs x 256x64
  u16* ldsA = lds;
  u16* ldsB = lds + 32768;

  // XCD-aware bijective remap (nwg % 8 == 0)
  int bx, by, bz;
  {
    const int gx = gridDim.x, gy = gridDim.y;
    const int lid = blockIdx.x + gx * (blockIdx.y + gy * blockIdx.z);
    const int nwg = gx * gy * gridDim.z;
    const int q = nwg >> 3;
    const int nid = (lid & 7) * q + (lid >> 3);
    bx = nid % gx;
    const int rem = nid / gx;
    by = rem % gy;
    bz = rem / gy;
  }

  const int tid = threadIdx.x;
  const int w = tid >> 6, l = tid & 63;
  const int m0 = by << 8, n0 = bx << 8;
  const int wr = w >> 2, wc = w & 3;  // 2(M) x 4(N) waves -> 128x64 per wave
  const int wr128 = wr * 128, wc64 = wc * 64;
  const int fr = l & 15, kx = l >> 4, fr7 = l & 7;
  const int srow = l >> 3;
  const int gsrc8 = (((l & 7) ^ ((l >> 3) & 7)) << 3);  // inverse-swizzled src granule

  const u16* sA0 = A0 + (size_t)bz * aBatch;
  const u16* sB0 = B0 + (size_t)bz * bBatch;
  const u16* sA1 = A1 + (size_t)bz * aBatch;
  const u16* sB1 = B1 + (size_t)bz * bBatch;
  float* Cb = C + (size_t)bz * M * N;

#define PICKAB(tt, Ap_, Bp_)                          \
  const u16 *Ap_ = sA0, *Bp_ = sB0;                   \
  if (NSEG > 1 && (tt) / TPS == 1) { Ap_ = sA1; Bp_ = sB1; }

  // A half h covers tile rows {h*64..h*64+63} u {128+h*64..+63}
#define STAGE_A(tt, h)                                                          \
  do {                                                                          \
    PICKAB(tt, Ap_, Bp_); (void)Bp_;                                            \
    const int kk_ = ((tt) % TPS) * 64;                                          \
    u16* d0_ = ldsA + ((tt) & 1) * 16384 + ((h) * 64 + w * 8) * 64;             \
    const u16* g0_ = Ap_ + (size_t)(m0 + (h) * 64 + w * 8 + srow) * lda + kk_ + gsrc8; \
    gload16(g0_, d0_);                                                          \
    gload16(g0_ + (size_t)128 * lda, d0_ + 128 * 64);                           \
  } while (0)

  // B half h covers tile rows { k*64 + h*32 .. +31 : k=0..3 }
#define STAGE_B(tt, h)                                                          \
  do {                                                                          \
    PICKAB(tt, Ap_, Bp_); (void)Ap_;                                            \
    const int kk_ = ((tt) % TPS) * 64;                                          \
    const int rb_ = (w >> 2) * 64 + (h) * 32 + (w & 3) * 8;                     \
    u16* d0_ = ldsB + ((tt) & 1) * 16384 + rb_ * 64;                            \
    const u16* g0_ = Bp_ + (size_t)(n0 + rb_ + srow) * ldb + kk_ + gsrc8;       \
    gload16(g0_, d0_);                                                          \
    gload16(g0_ + (size_t)128 * ldb, d0_ + 128 * 64);                           \
  } while (0)

#define RA8(MOFF)                                                                   \
  {                                                                                 \
    _Pragma("unroll") for (int m_ = 0; m_ < 4; ++m_) {                              \
      _Pragma("unroll") for (int k_ = 0; k_ < 2; ++k_) {                            \
        af[m_][k_] = *(const f16x8*)(ldsA + bufo +                                  \
            (wr128 + (MOFF) + m_ * 16 + fr) * 64 + (((kx + k_ * 4) ^ fr7) << 3));   \
      }                                                                             \
    }                                                                               \
  }

#define RB4(NF0)                                                                    \
  {                                                                                 \
    _Pragma("unroll") for (int n_ = 0; n_ < 2; ++n_) {                              \
      _Pragma("unroll") for (int k_ = 0; k_ < 2; ++k_) {                            \
        bf[(NF0) + n_][k_] = *(const f16x8*)(ldsB + bufo +                          \
            (wc64 + ((NF0) + n_) * 16 + fr) * 64 + (((kx + k_ * 4) ^ fr7) << 3));   \
      }                                                                             \
    }                                                                               \
  }

#define MFMA8(MF0, NF0)                                                             \
  {                                                                                 \
    _Pragma("unroll") for (int m_ = 0; m_ < 4; ++m_)                                \
    _Pragma("unroll") for (int n_ = 0; n_ < 2; ++n_)                                \
    _Pragma("unroll") for (int k_ = 0; k_ < 2; ++k_)                                \
        acc[(MF0) + m_][(NF0) + n_] = __builtin_amdgcn_mfma_f32_16x16x32_f16(       \
            af[m_][k_], bf[(NF0) + n_][k_], acc[(MF0) + m_][(NF0) + n_], 0, 0, 0);  \
  }

  f32x4 acc[8][4];
#pragma unroll
  for (int i = 0; i < 8; ++i)
#pragma unroll
    for (int j = 0; j < 4; ++j) acc[i][j] = (f32x4){0.f, 0.f, 0.f, 0.f};
  f16x8 af[4][2], bf[4][2];

  // Prologue: tile0 fully + tile1 {Ah0,Bh0,Ah1}; wait until tile0 landed.
  STAGE_A(0, 0); STAGE_A(0, 1); STAGE_B(0, 0); STAGE_B(0, 1);
  STAGE_A(1, 0); STAGE_B(1, 0); STAGE_A(1, 1);
  WAITVM(6);
  BARRIER();

#pragma unroll 2
  for (int t = 0; t < NT; ++t) {
    const int bufo = (t & 1) * 16384;
    // ---- ph0: read A-half0 frags + B nf0..1; stage (t+1).Bh1
    RA8(0);
    RB4(0);
    if (t + 1 < NT) STAGE_B(t + 1, 1);
    BARRIER();
    __builtin_amdgcn_s_setprio(1); MFMA8(0, 0); __builtin_amdgcn_s_setprio(0);
    BARRIER();
    // ---- ph1: read B nf2..3; stage (t+2).Ah0
    RB4(2);
    if (t + 2 < NT) STAGE_A(t + 2, 0);
    BARRIER();
    __builtin_amdgcn_s_setprio(1); MFMA8(0, 2); __builtin_amdgcn_s_setprio(0);
    BARRIER();
    // ---- ph2: read A-half1 frags; stage (t+2).Bh0
    RA8(64);
    if (t + 2 < NT) STAGE_B(t + 2, 0);
    BARRIER();
    __builtin_amdgcn_s_setprio(1); MFMA8(4, 0); __builtin_amdgcn_s_setprio(0);
    BARRIER();
    // ---- ph3: stage (t+2).Ah1; counted vmcnt so next tile is resident
    if (t + 2 < NT) STAGE_A(t + 2, 1);
    BARRIER();
    __builtin_amdgcn_s_setprio(1); MFMA8(4, 2); __builtin_amdgcn_s_setprio(0);
    if (t + 2 < NT) { WAITVM(6); } else if (t + 1 < NT) { WAITVM(0); }
    BARRIER();
  }

  // Epilogue: C/D layout col=lane&15, row=(lane>>4)*4+j
  const int crow = (l >> 4) * 4;
  const int ccol = l & 15;
#pragma unroll
  for (int mf = 0; mf < 8; ++mf)
#pragma unroll
    for (int nf = 0; nf < 4; ++nf) {
      float* cp = Cb + (size_t)(m0 + wr128 + mf * 16 + crow) * N + (n0 + wc64 + nf * 16 + ccol);
#pragma unroll
      for (int j = 0; j < 4; ++j) cp[(size_t)j * N] = acc[mf][nf][j];
    }
#undef PICKAB
#undef STAGE_A
#undef STAGE_B
#undef RA8
#undef RB4
#undef MFMA8
}

// ---------------- aux kernels ----------------
// Q fp32 [nrows][1024] -> Qh fp16
__global__ __launch_bounds__(256) void k_conv_q(const float* __restrict__ in,
                                                u16* __restrict__ hi_o, int nrows) {
  int t = blockIdx.x * 256 + threadIdx.x;
  int total = nrows * (DD_ / 4);
  if (t >= total) return;
  int row = t >> 8;
  int c4 = (t & 255) << 2;
  float4 v = *(const float4*)(in + (size_t)row * DD_ + c4);
  u16x4 hi;
  hi.x = f2h(v.x);
  hi.y = f2h(v.y);
  hi.z = f2h(v.z);
  hi.w = f2h(v.w);
  *(u16x4*)(hi_o + (size_t)row * DD_ + c4) = hi;
}

// V fp32 [LV][DD] -> Vh fp16 [LV][DD] + VT fp16 [DD][LV] (= Vh^T), 64x64 tiles
__global__ __launch_bounds__(256) void k_conv_vt(const float* __restrict__ V,
                                                 u16* __restrict__ Vh,
                                                 u16* __restrict__ VT) {
  __shared__ u16 tile[64][65];
  const int d0 = blockIdx.x * 64, v0 = blockIdx.y * 64;
  const size_t boff = (size_t)blockIdx.z * LV_ * DD_;
  const float* Vb = V + boff;
  u16* Vhb = Vh + boff;
  u16* VTb = VT + (size_t)blockIdx.z * DD_ * LV_;
  const int t = threadIdx.x;
  const int r = t >> 4, c4 = (t & 15) * 4;
#pragma unroll
  for (int i = 0; i < 4; ++i) {
    int row = r + i * 16;
    float4 x = *(const float4*)(Vb + (size_t)(v0 + row) * DD_ + d0 + c4);
    u16x4 h;
    h.x = f2h(x.x);
    h.y = f2h(x.y);
    h.z = f2h(x.z);
    h.w = f2h(x.w);
    *(u16x4*)(Vhb + (size_t)(v0 + row) * DD_ + d0 + c4) = h;
    tile[row][c4 + 0] = h.x;
    tile[row][c4 + 1] = h.y;
    tile[row][c4 + 2] = h.z;
    tile[row][c4 + 3] = h.w;
  }
  __syncthreads();
#pragma unroll
  for (int i = 0; i < 4; ++i) {
    int row = r + i * 16;
    u16x4 o;
    o.x = tile[c4 + 0][row];
    o.y = tile[c4 + 1][row];
    o.z = tile[c4 + 2][row];
    o.w = tile[c4 + 3][row];
    *(u16x4*)(VTb + (size_t)(d0 + row) * LV_ + v0 + c4) = o;
  }
}

// row softmax over S [nrows][2048] fp32 -> P fp16 (one wave per row)
__global__ __launch_bounds__(256) void k_softmax(const float* __restrict__ S,
                                                 u16* __restrict__ P, int nrows) {
  const int w = threadIdx.x >> 6, l = threadIdx.x & 63;
  const int row = blockIdx.x * 4 + w;
  if (row >= nrows) return;
  const float* s = S + (size_t)row * LV_;
  u16* p = P + (size_t)row * LV_;
  float4 v[8];
  float m = -3.0e38f;
#pragma unroll
  for (int i = 0; i < 8; ++i) {
    v[i] = *(const float4*)(s + (l << 2) + (i << 8));
    m = fmaxf(m, fmaxf(fmaxf(v[i].x, v[i].y), fmaxf(v[i].z, v[i].w)));
  }
#pragma unroll
  for (int off = 32; off > 0; off >>= 1) m = fmaxf(m, __shfl_xor(m, off, 64));
  float sum = 0.f;
#pragma unroll
  for (int i = 0; i < 8; ++i) {
    v[i].x = __expf(v[i].x - m);
    v[i].y = __expf(v[i].y - m);
    v[i].z = __expf(v[i].z - m);
    v[i].w = __expf(v[i].w - m);
    sum += v[i].x + v[i].y + v[i].z + v[i].w;
  }
#pragma unroll
  for (int off = 32; off > 0; off >>= 1) sum += __shfl_xor(sum, off, 64);
  const float inv = 1.0f / sum;
#pragma unroll
  for (int i = 0; i < 8; ++i) {
    u16x4 o;
    o.x = f2h(v[i].x * inv);
    o.y = f2h(v[i].y * inv);
    o.z = f2h(v[i].z * inv);
    o.w = f2h(v[i].w * inv);
    *(u16x4*)(p + (l << 2) + (i << 8)) = o;
  }
}

extern "C" void kernel_launch(void* const* d_in, const int* in_sizes, int n_in,
                              void* d_out, int out_size, void* d_ws, size_t ws_size,
                              hipStream_t stream) {
  const float* Q = (const float*)d_in[0];
  const float* V = (const float*)d_in[1];
  float* out = (float*)d_out;

  const size_t qv_e = (size_t)LQ_ * DD_;
  const size_t vt_e = (size_t)DD_ * LV_;
  const size_t s_e = (size_t)LQ_ * LV_;
  const size_t p_e = (size_t)LQ_ * LV_;
  const size_t per_batch = qv_e * 2 * 2 + vt_e * 2 + s_e * 4 + p_e * 2;  // 36 MiB

  int nb = (int)(ws_size / per_batch);
  if (nb < 1) nb = 1;
  if (nb > B_) nb = B_;

  char* wp = (char*)d_ws;
  u16* Qh = (u16*)wp; wp += (size_t)nb * qv_e * 2;
  u16* Vh = (u16*)wp; wp += (size_t)nb * qv_e * 2;
  u16* VT = (u16*)wp; wp += (size_t)nb * vt_e * 2;
  float* S = (float*)wp; wp += (size_t)nb * s_e * 4;
  u16* P = (u16*)wp;

  for (int b0 = 0; b0 < B_; b0 += nb) {
    const int cb = (nb < B_ - b0) ? nb : (B_ - b0);
    const int rows = cb * LQ_;
    const int cthreads = rows * (DD_ / 4);
    k_conv_q<<<dim3((cthreads + 255) / 256), dim3(256), 0, stream>>>(
        Q + (size_t)b0 * LQ_ * DD_, Qh, rows);
    k_conv_vt<<<dim3(DD_ / 64, LV_ / 64, cb), dim3(256), 0, stream>>>(
        V + (size_t)b0 * LV_ * DD_, Vh, VT);
    k_gemm8<1, 16><<<dim3(LV_ / 256, LQ_ / 256, cb), dim3(512), 0, stream>>>(
        Qh, Vh, Qh, Vh, S, LQ_, LV_, DD_, DD_, qv_e, qv_e);
    k_softmax<<<dim3(rows / 4), dim3(256), 0, stream>>>(S, P, rows);
    k_gemm8<1, 32><<<dim3(DD_ / 256, LQ_ / 256, cb), dim3(512), 0, stream>>>(
        P, VT, P, VT, out + (size_t)b0 * LQ_ * DD_, LQ_, DD_, LV_, LV_, p_e, vt_e);
  }
}